// Round 5
// baseline (1732.795 us; speedup 1.0000x reference)
//
#include <hip/hip_runtime.h>
#include <hip/hip_bf16.h>
#include <math.h>

#define B_ 2
#define L_ 1024
#define DM 768
#define DI 1536
#define DS 16
#define DR 48
#define NL 4
#define VOC 32000
#define BL (B_*L_)
#define NCH 32
#define LCH (L_/NCH)
#define KSPLIT 4
#define NXD 80   // fused x_dbl(64) + C(16) columns

typedef __attribute__((ext_vector_type(8))) short short8;
typedef __attribute__((ext_vector_type(4))) float f32x4;

__device__ __forceinline__ float sigmoidf_(float x){ return 1.f/(1.f+expf(-x)); }
__device__ __forceinline__ float siluf_(float x){ return x*sigmoidf_(x); }
__device__ __forceinline__ float softplusf_(float x){ return fmaxf(x,0.f) + log1pf(expf(-fabsf(x))); }
__device__ __forceinline__ unsigned short f2bf(float f){
    unsigned u = __float_as_uint(f);
    u += 0x7FFFu + ((u >> 16) & 1u);
    return (unsigned short)(u >> 16);
}
__device__ __forceinline__ float bf2f(unsigned short h){
    return __uint_as_float((unsigned)h << 16);
}
__device__ __forceinline__ void gload_lds16(const unsigned short* g, unsigned short* l){
    __builtin_amdgcn_global_load_lds(
        (const __attribute__((address_space(1))) void*)g,
        (__attribute__((address_space(3))) void*)l, 16, 0, 0);
}

// ---------------- fp32 -> bf16 cast (single) ----------------
__global__ void cast_bf16_kernel(const float* __restrict__ in, unsigned short* __restrict__ out, int n4)
{
    for (int i = blockIdx.x*256 + threadIdx.x; i < n4; i += gridDim.x*256) {
        float4 v = ((const float4*)in)[i];
        ushort4 o;
        o.x = f2bf(v.x); o.y = f2bf(v.y); o.z = f2bf(v.z); o.w = f2bf(v.w);
        ((ushort4*)out)[i] = o;
    }
}

// ---------------- fp32 -> bf16 hi/lo for 3 arrays in one dispatch ----------------
__global__ void cast_pair3_kernel(
    const float* __restrict__ s1, unsigned short* __restrict__ h1, unsigned short* __restrict__ l1, int n1,
    const float* __restrict__ s2, unsigned short* __restrict__ h2, unsigned short* __restrict__ l2, int n2,
    const float* __restrict__ s3, unsigned short* __restrict__ h3, unsigned short* __restrict__ l3, int n3)
{
    int total = n1 + n2 + n3;
    for (int i = blockIdx.x*256 + threadIdx.x; i < total; i += gridDim.x*256) {
        const float* s; unsigned short *h, *l; int j;
        if (i < n1)           { s = s1; h = h1; l = l1; j = i; }
        else if (i < n1 + n2) { s = s2; h = h2; l = l2; j = i - n1; }
        else                  { s = s3; h = h3; l = l3; j = i - n1 - n2; }
        float4 v = ((const float4*)s)[j];
        ushort4 hh, ll;
        hh.x = f2bf(v.x); ll.x = f2bf(v.x - bf2f(hh.x));
        hh.y = f2bf(v.y); ll.y = f2bf(v.y - bf2f(hh.y));
        hh.z = f2bf(v.z); ll.z = f2bf(v.z - bf2f(hh.z));
        hh.w = f2bf(v.w); ll.w = f2bf(v.w - bf2f(hh.w));
        ((ushort4*)h)[j] = hh;
        ((ushort4*)l)[j] = ll;
    }
}

// ---------------- embedding gather ----------------
__global__ void embed_kernel(const int* __restrict__ idx, const float* __restrict__ emb,
                             float* __restrict__ x)
{
    int i = blockIdx.x*256 + threadIdx.x;        // over BL*DM
    if (i >= BL*DM) return;
    int c = i % DM; int bl = i / DM;
    x[i] = emb[(size_t)idx[bl]*DM + c];
}

// ---------------- rmsnorm single (bf16 out) ----------------
__global__ void rmsnorm_bf_kernel(const float* __restrict__ in, const float* __restrict__ w,
                                  unsigned short* __restrict__ out)
{
    int row = blockIdx.x;
    const float* xr = in + (size_t)row*DM;
    float ss = 0.f;
    for (int c = threadIdx.x; c < DM; c += 256) { float v = xr[c]; ss += v*v; }
    #pragma unroll
    for (int o = 32; o > 0; o >>= 1) ss += __shfl_down(ss, o, 64);
    __shared__ float red[4];
    if ((threadIdx.x & 63) == 0) red[threadIdx.x >> 6] = ss;
    __syncthreads();
    float tot = red[0] + red[1] + red[2] + red[3];
    float scale = rsqrtf(tot * (1.f/DM) + 1e-5f);
    for (int c = threadIdx.x; c < DM; c += 256)
        out[(size_t)row*DM + c] = f2bf(xr[c]*scale*w[c]);
}

// ---------------- rmsnorm dual (q from x, v from visual), hi/lo bf16 out ------
__global__ void rmsnorm_dual_kernel(const float* __restrict__ x, const float* __restrict__ vis,
                                    const float* __restrict__ w,
                                    unsigned short* __restrict__ qh, unsigned short* __restrict__ ql,
                                    unsigned short* __restrict__ vh, unsigned short* __restrict__ vl)
{
    int row = blockIdx.x;                        // 0..2*BL-1
    bool first = row < BL;
    int r = first ? row : row - BL;
    const float* xr = (first ? x : vis) + (size_t)r*DM;
    unsigned short* oh = (first ? qh : vh) + (size_t)r*DM;
    unsigned short* ol = (first ? ql : vl) + (size_t)r*DM;
    float ss = 0.f;
    for (int c = threadIdx.x; c < DM; c += 256) { float v = xr[c]; ss += v*v; }
    #pragma unroll
    for (int o = 32; o > 0; o >>= 1) ss += __shfl_down(ss, o, 64);
    __shared__ float red[4];
    if ((threadIdx.x & 63) == 0) red[threadIdx.x >> 6] = ss;
    __syncthreads();
    float tot = red[0] + red[1] + red[2] + red[3];
    float scale = rsqrtf(tot * (1.f/DM) + 1e-5f);
    for (int c = threadIdx.x; c < DM; c += 256) {
        float v = xr[c]*scale*w[c];
        unsigned short h = f2bf(v);
        oh[c] = h;
        ol[c] = f2bf(v - bf2f(h));
    }
}

// ---------------- lm_head bf16 MFMA GEMM (grid x=M/128, y=N/128) ----------------
// XCD-chunked bijective swizzle; bm-fastest decode -> each XCD owns a contiguous
// N-slice whose B panels stay L2-resident across all 16 M blocks. Plain cached
// stores (NT sub-line stores regressed: RMW at HBM).
__global__ __launch_bounds__(256) void gemm_head(
    const unsigned short* __restrict__ A, int lda,
    const unsigned short* __restrict__ W, int ldb,
    float* __restrict__ C, int ldc, int K)
{
    __shared__ unsigned short As[128*64];
    __shared__ unsigned short Bs[128*64];
    const int tid = threadIdx.x;

    int nwg  = gridDim.x*gridDim.y;
    int flat = blockIdx.y*gridDim.x + blockIdx.x;
    if ((nwg & 7) == 0) {
        int q = nwg >> 3;
        flat = (flat & 7)*q + (flat >> 3);   // contiguous logical chunk per XCD
    }
    const int bm = (flat % gridDim.x)*128;
    const int bn = (flat / gridDim.x)*128;

    const int l  = tid & 63;
    const int w  = tid >> 6;
    const int wr = (w >> 1)*64, wc = (w & 1)*64;
    const int lr = l & 15, lg = l >> 4;

    f32x4 zero4 = {0.f, 0.f, 0.f, 0.f};
    f32x4 acc[4][4];
    #pragma unroll
    for (int m = 0; m < 4; m++)
        #pragma unroll
        for (int n = 0; n < 4; n++) acc[m][n] = zero4;

    for (int k0 = 0; k0 < K; k0 += 64) {
        __syncthreads();
        #pragma unroll
        for (int i = 0; i < 4; i++) {
            int c   = i*256 + tid;
            int row = c >> 3;
            int kb  = c & 7;
            int kbs = (kb ^ (row & 7)) << 3;
            gload_lds16(A + (size_t)(bm+row)*lda + k0 + kbs, &As[c*8]);
            gload_lds16(W + (size_t)(bn+row)*ldb + k0 + kbs, &Bs[c*8]);
        }
        __syncthreads();
        #pragma unroll
        for (int kk = 0; kk < 2; kk++) {
            short8 af[4], bfr[4];
            #pragma unroll
            for (int m = 0; m < 4; m++) {
                int row = wr + m*16 + lr;
                af[m] = *(const short8*)&As[row*64 + (((kk*4+lg) ^ (row & 7)) << 3)];
            }
            #pragma unroll
            for (int n = 0; n < 4; n++) {
                int row = wc + n*16 + lr;
                bfr[n] = *(const short8*)&Bs[row*64 + (((kk*4+lg) ^ (row & 7)) << 3)];
            }
            #pragma unroll
            for (int m = 0; m < 4; m++)
                #pragma unroll
                for (int n = 0; n < 4; n++)
                    acc[m][n] = __builtin_amdgcn_mfma_f32_16x16x32_bf16(af[m], bfr[n], acc[m][n], 0, 0, 0);
        }
    }

    #pragma unroll
    for (int m = 0; m < 4; m++)
        #pragma unroll
        for (int n = 0; n < 4; n++) {
            int col = bn + wc + n*16 + lr;
            #pragma unroll
            for (int r = 0; r < 4; r++) {
                int rowi = bm + wr + m*16 + lg*4 + r;
                C[(size_t)rowi*ldc + col] = acc[m][n][r];
            }
        }
}

// ---------------- split-bf16 (hi/lo) MFMA GEMM core, BK=32 ----------------
// 4 LDS buffers x 8KB = 32KB -> 4 blocks/CU (vs 64KB/2 blocks at BK=64).
template<int EPI>
__device__ __forceinline__ void mfma2_body(
    const unsigned short* __restrict__ Ah, const unsigned short* __restrict__ Alo, int lda,
    const unsigned short* __restrict__ Wh, const unsigned short* __restrict__ Wlo, int ldb,
    float* __restrict__ C, int ldc, const float* __restrict__ extra,
    int K, int bm, int bn,
    unsigned short* Ash, unsigned short* Asl, unsigned short* Bsh, unsigned short* Bsl)
{
    const int tid = threadIdx.x;
    const int l  = tid & 63;
    const int w  = tid >> 6;
    const int wr = (w >> 1)*64, wc = (w & 1)*64;
    const int lr = l & 15, lg = l >> 4;

    f32x4 zero4 = {0.f, 0.f, 0.f, 0.f};
    f32x4 acc[4][4];
    #pragma unroll
    for (int m = 0; m < 4; m++)
        #pragma unroll
        for (int n = 0; n < 4; n++) acc[m][n] = zero4;

    for (int k0 = 0; k0 < K; k0 += 32) {
        __syncthreads();
        #pragma unroll
        for (int i = 0; i < 2; i++) {
            int c   = i*256 + tid;           // 512 chunks of 16B per tile
            int row = c >> 2;
            int kb  = c & 3;
            int kbs = (kb ^ (row & 3)) << 3;
            const size_t ao = (size_t)(bm+row)*lda + k0 + kbs;
            const size_t bo = (size_t)(bn+row)*ldb + k0 + kbs;
            gload_lds16(Ah  + ao, &Ash[c*8]);
            gload_lds16(Alo + ao, &Asl[c*8]);
            gload_lds16(Wh  + bo, &Bsh[c*8]);
            gload_lds16(Wlo + bo, &Bsl[c*8]);
        }
        __syncthreads();
        short8 ah[4], al[4], bh[4], bl[4];
        #pragma unroll
        for (int m = 0; m < 4; m++) {
            int row = wr + m*16 + lr;
            int so  = row*32 + ((lg ^ (row & 3)) << 3);
            ah[m] = *(const short8*)&Ash[so];
            al[m] = *(const short8*)&Asl[so];
        }
        #pragma unroll
        for (int n = 0; n < 4; n++) {
            int row = wc + n*16 + lr;
            int so  = row*32 + ((lg ^ (row & 3)) << 3);
            bh[n] = *(const short8*)&Bsh[so];
            bl[n] = *(const short8*)&Bsl[so];
        }
        #pragma unroll
        for (int m = 0; m < 4; m++)
            #pragma unroll
            for (int n = 0; n < 4; n++) {
                acc[m][n] = __builtin_amdgcn_mfma_f32_16x16x32_bf16(al[m], bh[n], acc[m][n], 0, 0, 0);
                acc[m][n] = __builtin_amdgcn_mfma_f32_16x16x32_bf16(ah[m], bl[n], acc[m][n], 0, 0, 0);
                acc[m][n] = __builtin_amdgcn_mfma_f32_16x16x32_bf16(ah[m], bh[n], acc[m][n], 0, 0, 0);
            }
    }

    #pragma unroll
    for (int m = 0; m < 4; m++)
        #pragma unroll
        for (int n = 0; n < 4; n++) {
            int col = bn + wc + n*16 + lr;
            #pragma unroll
            for (int r = 0; r < 4; r++) {
                int rowi = bm + wr + m*16 + lg*4 + r;
                float v = acc[m][n][r];
                if (EPI == 1) v += extra[(size_t)rowi*ldc + col];
                C[(size_t)rowi*ldc + col] = v;
            }
        }
}

// single split GEMM (out_proj, EPI=1 residual)
template<int EPI>
__global__ __launch_bounds__(256) void gemm_mfma2(
    const unsigned short* __restrict__ Ah, const unsigned short* __restrict__ Alo, int lda,
    const unsigned short* __restrict__ Wh, const unsigned short* __restrict__ Wlo, int ldb,
    float* __restrict__ C, int ldc, const float* __restrict__ extra, int K)
{
    __shared__ unsigned short Ash[128*32];
    __shared__ unsigned short Asl[128*32];
    __shared__ unsigned short Bsh[128*32];
    __shared__ unsigned short Bsl[128*32];
    mfma2_body<EPI>(Ah, Alo, lda, Wh, Wlo, ldb, C, ldc, extra, K,
                    blockIdx.y*128, blockIdx.x*128, Ash, Asl, Bsh, Bsl);
}

// dual split GEMM with XCD-chunked swizzle (bm-fastest decode).
// logical bx in [0,nb1) -> GEMM1, [nb1,..) -> GEMM2 (shared lda/ldb/K)
__global__ __launch_bounds__(256) void gemm_mfma2_dual(
    const unsigned short* __restrict__ Ah1, const unsigned short* __restrict__ Al1,
    const unsigned short* __restrict__ Wh1, const unsigned short* __restrict__ Wl1,
    float* __restrict__ C1, int ldc1, int nb1,
    const unsigned short* __restrict__ Ah2, const unsigned short* __restrict__ Al2,
    const unsigned short* __restrict__ Wh2, const unsigned short* __restrict__ Wl2,
    float* __restrict__ C2, int ldc2,
    int lda, int ldb, int K)
{
    __shared__ unsigned short Ash[128*32];
    __shared__ unsigned short Asl[128*32];
    __shared__ unsigned short Bsh[128*32];
    __shared__ unsigned short Bsl[128*32];
    int nwg  = gridDim.x*gridDim.y;
    int flat = blockIdx.y*gridDim.x + blockIdx.x;
    if ((nwg & 7) == 0) {
        int q = nwg >> 3;
        flat = (flat & 7)*q + (flat >> 3);
    }
    int by = flat % gridDim.y;    // M-block (fastest -> same-XCD blocks share W panel)
    int bx = flat / gridDim.y;
    if (bx < nb1)
        mfma2_body<0>(Ah1, Al1, lda, Wh1, Wl1, ldb, C1, ldc1, nullptr, K,
                      by*128, bx*128, Ash, Asl, Bsh, Bsl);
    else
        mfma2_body<0>(Ah2, Al2, lda, Wh2, Wl2, ldb, C2, ldc2, nullptr, K,
                      by*128, (bx-nb1)*128, Ash, Asl, Bsh, Bsl);
}

// ---------------- fp32 tile GEMM (dt_proj, K=48, EPI=2 softplus+bias) ----------
template<int EPI>
__global__ __launch_bounds__(256) void gemm_tile(
    const float* __restrict__ A, int lda,
    const float* __restrict__ W, int ldb,
    float* __restrict__ C, int ldc,
    const float* __restrict__ extra,
    int K)
{
    __shared__ float As[8][128];
    __shared__ float Bs[8][128];
    const int bm = blockIdx.y * 128;
    const int bn = blockIdx.x * 128;
    const int tid = threadIdx.x;
    const int lr = tid >> 1;
    const int lh = (tid & 1) * 4;
    const int tr = tid >> 4;
    const int tc = tid & 15;

    float acc[8][8];
    #pragma unroll
    for (int i = 0; i < 8; i++)
        #pragma unroll
        for (int j = 0; j < 8; j++) acc[i][j] = 0.f;

    const float* Arow = A + (size_t)(bm + lr)*lda + lh;
    const float* Wrow = W + (size_t)(bn + lr)*ldb + lh;

    for (int k0 = 0; k0 < K; k0 += 8) {
        float4 av = *(const float4*)(Arow + k0);
        float4 wv = *(const float4*)(Wrow + k0);
        __syncthreads();
        As[lh+0][lr] = av.x; As[lh+1][lr] = av.y; As[lh+2][lr] = av.z; As[lh+3][lr] = av.w;
        Bs[lh+0][lr] = wv.x; Bs[lh+1][lr] = wv.y; Bs[lh+2][lr] = wv.z; Bs[lh+3][lr] = wv.w;
        __syncthreads();
        #pragma unroll
        for (int k = 0; k < 8; k++) {
            float a[8], b[8];
            *(float4*)(a)   = *(const float4*)&As[k][tr*8];
            *(float4*)(a+4) = *(const float4*)&As[k][tr*8+4];
            *(float4*)(b)   = *(const float4*)&Bs[k][tc*8];
            *(float4*)(b+4) = *(const float4*)&Bs[k][tc*8+4];
            #pragma unroll
            for (int i = 0; i < 8; i++)
                #pragma unroll
                for (int j = 0; j < 8; j++)
                    acc[i][j] = fmaf(a[i], b[j], acc[i][j]);
        }
    }

    #pragma unroll
    for (int i = 0; i < 8; i++) {
        int row = bm + tr*8 + i;
        float* crow = C + (size_t)row*ldc + bn + tc*8;
        float v[8];
        if (EPI == 2) {
            const float* bia = extra + bn + tc*8;
            #pragma unroll
            for (int j = 0; j < 8; j++) v[j] = softplusf_(acc[i][j] + bia[j]);
        } else {
            #pragma unroll
            for (int j = 0; j < 8; j++) v[j] = acc[i][j];
        }
        *(float4*)(crow)   = make_float4(v[0],v[1],v[2],v[3]);
        *(float4*)(crow+4) = make_float4(v[4],v[5],v[6],v[7]);
    }
}

// ---------------- fused skinny split-K: x_dbl (64 cols) + C (16 cols) --------
__global__ __launch_bounds__(256) void gemm_skinny2(
    const float* __restrict__ A1, const float* __restrict__ A2, int lda,
    const float* __restrict__ W1, const float* __restrict__ W2, int ldb,
    float* __restrict__ partial, int K)
{
    int klen = K / gridDim.z;
    int kbeg = blockIdx.z * klen;
    __shared__ float As[64][36];
    __shared__ float Ws[16][36];
    int tid = threadIdx.x;
    int bx = blockIdx.x;
    bool isC = (bx == 4);
    const float* A = isC ? A2 : A1;
    const float* W = isC ? W2 : W1;
    int bn = isC ? 0 : bx*16;
    int colbase = isC ? 64 : bx*16;
    int bm = blockIdx.y*64;
    int ar = tid >> 2, ak = (tid & 3)*8;
    int wr = tid >> 4, wk = (tid & 15)*2;
    int tr = tid >> 4, tc = tid & 15;

    float acc[4] = {0.f,0.f,0.f,0.f};
    for (int k0 = kbeg; k0 < kbeg + klen; k0 += 32) {
        float4 a0 = *(const float4*)(A + (size_t)(bm+ar)*lda + k0 + ak);
        float4 a1 = *(const float4*)(A + (size_t)(bm+ar)*lda + k0 + ak + 4);
        float2 wv = *(const float2*)(W + (size_t)(bn+wr)*ldb + k0 + wk);
        __syncthreads();
        *(float4*)&As[ar][ak]   = a0;
        *(float4*)&As[ar][ak+4] = a1;
        Ws[wr][wk] = wv.x; Ws[wr][wk+1] = wv.y;
        __syncthreads();
        #pragma unroll
        for (int k = 0; k < 32; k += 4) {
            float4 wv4 = *(const float4*)&Ws[tc][k];
            #pragma unroll
            for (int i = 0; i < 4; i++) {
                float4 av4 = *(const float4*)&As[tr*4+i][k];
                acc[i] = fmaf(av4.x, wv4.x, acc[i]);
                acc[i] = fmaf(av4.y, wv4.y, acc[i]);
                acc[i] = fmaf(av4.z, wv4.z, acc[i]);
                acc[i] = fmaf(av4.w, wv4.w, acc[i]);
            }
        }
    }
    #pragma unroll
    for (int i = 0; i < 4; i++)
        partial[((size_t)blockIdx.z*BL + bm + tr*4 + i)*NXD + colbase + tc] = acc[i];
}

__global__ void reduce_splitk(const float* __restrict__ partial, float* __restrict__ out, int MN)
{
    int i = blockIdx.x*256 + threadIdx.x;
    if (i >= MN) return;
    float s = 0.f;
    #pragma unroll
    for (int z = 0; z < KSPLIT; z++) s += partial[(size_t)z*MN + i];
    out[i] = s;
}

// ---------------- depthwise causal conv (k=4) + bias + silu ----------------
__global__ void conv_silu_kernel(const float* __restrict__ xr, const float* __restrict__ cw,
                                 const float* __restrict__ cb, float* __restrict__ t)
{
    int i = blockIdx.x*256 + threadIdx.x;     // over BL*DI
    if (i >= BL*DI) return;
    int d = i % DI; int bl = i / DI; int l = bl % L_; int b = bl / L_;
    const float* base = xr + (size_t)b*L_*(2*DI);
    float acc = cb[d];
    #pragma unroll
    for (int q = 0; q < 4; q++) {
        int ll = l - 3 + q;
        if (ll >= 0) acc = fmaf(base[(size_t)ll*(2*DI) + d], cw[d*4+q], acc);
    }
    t[i] = siluf_(acc);
}

// ---------------- chunked selective scan ----------------
__global__ void scan_p1(const float* __restrict__ delta, const float* __restrict__ t,
                        const float* __restrict__ xdbl, const float* __restrict__ A_log,
                        float* __restrict__ Aprod, float* __restrict__ Bacc)
{
    int idx = blockIdx.x*256 + threadIdx.x;   // (b*NCH + c)*DI + d
    if (idx >= B_*NCH*DI) return;
    int d = idx % DI; int c = (idx/DI) % NCH; int b = idx/(DI*NCH);
    float Ad[16];
    #pragma unroll
    for (int n = 0; n < 16; n++) Ad[n] = -expf(A_log[d*16+n]);
    float P[16], S[16];
    #pragma unroll
    for (int n = 0; n < 16; n++) { P[n] = 1.f; S[n] = 0.f; }
    for (int s = 0; s < LCH; s++) {
        int bl = b*L_ + c*LCH + s;
        float dt = delta[(size_t)bl*DI + d];
        float u  = t[(size_t)bl*DI + d];
        const float4* Bp4 = (const float4*)(xdbl + (size_t)bl*NXD + 48);
        float Bv[16];
        #pragma unroll
        for (int q = 0; q < 4; q++) {
            float4 bv = Bp4[q];
            Bv[q*4+0]=bv.x; Bv[q*4+1]=bv.y; Bv[q*4+2]=bv.z; Bv[q*4+3]=bv.w;
        }
        float du = dt*u;
        #pragma unroll
        for (int n = 0; n < 16; n++) {
            float a  = expf(dt*Ad[n]);
            P[n] *= a;
            S[n] = fmaf(a, S[n], du*Bv[n]);
        }
    }
    size_t o = (size_t)idx*16;
    #pragma unroll
    for (int n = 0; n < 16; n++) { Aprod[o+n] = P[n]; Bacc[o+n] = S[n]; }
}

// pass2: parallel over (b,d,n) -- coalesced on n, 192 blocks
__global__ void scan_p2(const float* __restrict__ Aprod, const float* __restrict__ Bacc,
                        float* __restrict__ Hinit)
{
    int idx = blockIdx.x*256 + threadIdx.x;   // (b*DI + d)*16 + n
    if (idx >= B_*DI*DS) return;
    int bd = idx >> 4;                         // b*DI + d
    int n  = idx & 15;
    int b  = bd / DI, d = bd % DI;
    float h = 0.f;
    for (int c = 0; c < NCH; c++) {
        size_t o = (((size_t)b*NCH + c)*DI + d)*16 + n;
        Hinit[o] = h;
        h = fmaf(Aprod[o], h, Bacc[o]);
    }
}

// pass3: replay + fuse y = scan + u*D, z = y*silu(res) -> bf16 hi/lo out
__global__ void scan_p3(const float* __restrict__ delta, const float* __restrict__ t,
                        const float* __restrict__ xdbl,
                        const float* __restrict__ A_log, const float* __restrict__ Dp,
                        const float* __restrict__ Hinit, const float* __restrict__ xr,
                        unsigned short* __restrict__ zh, unsigned short* __restrict__ zl)
{
    int idx = blockIdx.x*256 + threadIdx.x;
    if (idx >= B_*NCH*DI) return;
    int d = idx % DI; int c = (idx/DI) % NCH; int b = idx/(DI*NCH);
    float Ad[16];
    #pragma unroll
    for (int n = 0; n < 16; n++) Ad[n] = -expf(A_log[d*16+n]);
    float h[16];
    size_t ho = (size_t)idx*16;
    #pragma unroll
    for (int n = 0; n < 16; n++) h[n] = Hinit[ho+n];
    float Dd = Dp[d];
    for (int s = 0; s < LCH; s++) {
        int bl = b*L_ + c*LCH + s;
        float dt = delta[(size_t)bl*DI + d];
        float u  = t[(size_t)bl*DI + d];
        const float4* Bp4 = (const float4*)(xdbl + (size_t)bl*NXD + 48);
        const float4* Cp4 = (const float4*)(xdbl + (size_t)bl*NXD + 64);
        float Bv[16], Cv[16];
        #pragma unroll
        for (int q = 0; q < 4; q++) {
            float4 bv = Bp4[q]; float4 cv = Cp4[q];
            Bv[q*4+0]=bv.x; Bv[q*4+1]=bv.y; Bv[q*4+2]=bv.z; Bv[q*4+3]=bv.w;
            Cv[q*4+0]=cv.x; Cv[q*4+1]=cv.y; Cv[q*4+2]=cv.z; Cv[q*4+3]=cv.w;
        }
        float du = dt*u;
        float y = 0.f;
        #pragma unroll
        for (int n = 0; n < 16; n++) {
            float a = expf(dt*Ad[n]);
            h[n] = fmaf(a, h[n], du*Bv[n]);
            y = fmaf(h[n], Cv[n], y);
        }
        y = fmaf(u, Dd, y);
        float r = xr[(size_t)bl*(2*DI) + DI + d];
        float zv = y * siluf_(r);
        unsigned short hh = f2bf(zv);
        zh[(size_t)bl*DI + d] = hh;
        zl[(size_t)bl*DI + d] = f2bf(zv - bf2f(hh));
    }
}

// ---------------- host ----------------
extern "C" void kernel_launch(void* const* d_in, const int* in_sizes, int n_in,
                              void* d_out, int out_size, void* d_ws, size_t ws_size,
                              hipStream_t stream)
{
    const int*   text     = (const int*)  d_in[0];
    const float* visual   = (const float*)d_in[1];
    const float* emb      = (const float*)d_in[2];
    const float* norm_w   = (const float*)d_in[3];
    const float* norm_f_w = (const float*)d_in[4];
    const float* in_proj  = (const float*)d_in[5];
    const float* in_proj2 = (const float*)d_in[6];
    const float* conv_w   = (const float*)d_in[7];
    const float* conv_b   = (const float*)d_in[8];
    const float* x_proj   = (const float*)d_in[9];
    const float* c_proj   = (const float*)d_in[10];
    const float* dt_w     = (const float*)d_in[11];
    const float* dt_b     = (const float*)d_in[12];
    const float* A_log    = (const float*)d_in[13];
    const float* Dp       = (const float*)d_in[14];
    const float* out_proj = (const float*)d_in[15];
    float* out = (float*)d_out;

    // workspace layout (floats first)
    float* ws = (float*)d_ws;
    size_t off = 0;
    float* x     = ws + off; off += (size_t)BL*DM;
    float* xr    = ws + off; off += (size_t)BL*2*DI;
    float* vin   = ws + off; off += (size_t)BL*DI;
    float* tb    = ws + off; off += (size_t)BL*DI;
    float* dl    = ws + off; off += (size_t)BL*DI;
    float* xdbl  = ws + off; off += (size_t)BL*NXD;
    float* Aprod = ws + off; off += (size_t)B_*NCH*DI*DS;
    float* Bacc  = ws + off; off += (size_t)B_*NCH*DI*DS;
    float* Hinit = ws + off; off += (size_t)B_*NCH*DI*DS;
    float* part  = ws + off; off += (size_t)KSPLIT*BL*NXD;

    unsigned short* bfb = (unsigned short*)(ws + off);
    size_t bo = 0;
    unsigned short* emb_bf = bfb + bo; bo += (size_t)VOC*DM;
    unsigned short* wA_h   = bfb + bo; bo += (size_t)2*DI*DM;
    unsigned short* wA_l   = bfb + bo; bo += (size_t)2*DI*DM;
    unsigned short* wB_h   = bfb + bo; bo += (size_t)DI*DM;
    unsigned short* wB_l   = bfb + bo; bo += (size_t)DI*DM;
    unsigned short* wO_h   = bfb + bo; bo += (size_t)DM*DI;
    unsigned short* wO_l   = bfb + bo; bo += (size_t)DM*DI;
    unsigned short* q_h    = bfb + bo; bo += (size_t)BL*DM;
    unsigned short* q_l    = bfb + bo; bo += (size_t)BL*DM;
    unsigned short* v_h    = bfb + bo; bo += (size_t)BL*DM;
    unsigned short* v_l    = bfb + bo; bo += (size_t)BL*DM;
    unsigned short* z_h    = bfb + bo; bo += (size_t)BL*DI;
    unsigned short* z_l    = bfb + bo; bo += (size_t)BL*DI;
    unsigned short* xn_bf  = bfb + bo; bo += (size_t)BL*DM;

    dim3 blk(256);
    dim3 cgrid(2048);

    // embedding cast once (lm_head B operand)
    cast_bf16_kernel<<<cgrid, blk, 0, stream>>>(emb, emb_bf, VOC*DM/4);

    embed_kernel<<<dim3((BL*DM)/256), blk, 0, stream>>>(text, emb, x);

    for (int i = 0; i < NL; i++) {
        const float* nw = norm_w + (size_t)i*DM;

        // q = rmsnorm(x), v = rmsnorm(visual) -> hi/lo, one dispatch
        rmsnorm_dual_kernel<<<dim3(2*BL), blk, 0, stream>>>(
            x, visual, nw, q_h, q_l, v_h, v_l);

        // per-layer weight hi/lo casts, one dispatch
        cast_pair3_kernel<<<cgrid, blk, 0, stream>>>(
            in_proj  + (size_t)i*2*DI*DM, wA_h, wA_l, 2*DI*DM/4,
            in_proj2 + (size_t)i*DI*DM,   wB_h, wB_l, DI*DM/4,
            out_proj + (size_t)i*DM*DI,   wO_h, wO_l, DM*DI/4);

        // xr = q @ in_proj^T (N=3072) ++ vin = v @ in_proj2^T (N=1536), fused
        gemm_mfma2_dual<<<dim3(2*DI/128 + DI/128, BL/128), blk, 0, stream>>>(
            q_h, q_l, wA_h, wA_l, xr, 2*DI, 2*DI/128,
            v_h, v_l, wB_h, wB_l, vin, DI,
            DM, DM, DM);

        conv_silu_kernel<<<dim3((BL*DI)/256), blk, 0, stream>>>(
            xr, conv_w + (size_t)i*DI*4, conv_b + (size_t)i*DI, tb);

        // x_dbl (t @ x_proj^T) ++ C (vin @ c_proj^T), fused split-K -> xdbl[BL][80]
        gemm_skinny2<<<dim3(5, BL/64, KSPLIT), blk, 0, stream>>>(
            tb, vin, DI, x_proj + (size_t)i*(DR+DS)*DI, c_proj + (size_t)i*DS*DI, DI,
            part, DI);
        reduce_splitk<<<dim3((BL*NXD)/256), blk, 0, stream>>>(part, xdbl, BL*NXD);

        // delta = softplus(x_dbl[:, :48] @ dt_w^T + dt_b) fp32
        gemm_tile<2><<<dim3(DI/128, BL/128), blk, 0, stream>>>(
            xdbl, NXD, dt_w + (size_t)i*DI*DR, DR, dl, DI, dt_b + (size_t)i*DI, DR);

        // selective scan (chunked, 3 passes) -> z hi/lo
        const float* Al = A_log + (size_t)i*DI*DS;
        scan_p1<<<dim3((B_*NCH*DI)/256), blk, 0, stream>>>(dl, tb, xdbl, Al, Aprod, Bacc);
        scan_p2<<<dim3((B_*DI*DS)/256), blk, 0, stream>>>(Aprod, Bacc, Hinit);
        scan_p3<<<dim3((B_*NCH*DI)/256), blk, 0, stream>>>(dl, tb, xdbl, Al,
            Dp + (size_t)i*DI, Hinit, xr, z_h, z_l);

        // x = z @ out_proj^T + x (split precision)
        gemm_mfma2<1><<<dim3(DM/128, BL/128), blk, 0, stream>>>(
            z_h, z_l, DI, wO_h, wO_l, DI, x, DM, x, DI);
    }

    rmsnorm_bf_kernel<<<dim3(BL), blk, 0, stream>>>(x, norm_f_w, xn_bf);
    // logits = xn @ emb^T (2048 x 32000, K=768), grid x=M-blocks, y=N-blocks
    gemm_head<<<dim3(BL/128, VOC/128), blk, 0, stream>>>(
        xn_bf, DM, emb_bf, DM, out, VOC, DM);
}

// Round 6
// 1586.612 us; speedup vs baseline: 1.0921x; 1.0921x over previous
//
#include <hip/hip_runtime.h>
#include <hip/hip_bf16.h>
#include <math.h>

#define B_ 2
#define L_ 1024
#define DM 768
#define DI 1536
#define DS 16
#define DR 48
#define NL 4
#define VOC 32000
#define BL (B_*L_)
#define NCH 32
#define LCH (L_/NCH)
#define NXD 80   // fused x_dbl(64) + C(16) columns
#define DTILE 8

typedef __attribute__((ext_vector_type(8))) short short8;
typedef __attribute__((ext_vector_type(4))) float f32x4;

__device__ __forceinline__ float sigmoidf_(float x){ return 1.f/(1.f+expf(-x)); }
__device__ __forceinline__ float siluf_(float x){ return x*sigmoidf_(x); }
__device__ __forceinline__ float softplusf_(float x){ return fmaxf(x,0.f) + log1pf(expf(-fabsf(x))); }
__device__ __forceinline__ unsigned short f2bf(float f){
    unsigned u = __float_as_uint(f);
    u += 0x7FFFu + ((u >> 16) & 1u);
    return (unsigned short)(u >> 16);
}
__device__ __forceinline__ float bf2f(unsigned short h){
    return __uint_as_float((unsigned)h << 16);
}
__device__ __forceinline__ void gload_lds16(const unsigned short* g, unsigned short* l){
    __builtin_amdgcn_global_load_lds(
        (const __attribute__((address_space(1))) void*)g,
        (__attribute__((address_space(3))) void*)l, 16, 0, 0);
}

// ---------------- fp32 -> bf16 cast (single) ----------------
__global__ void cast_bf16_kernel(const float* __restrict__ in, unsigned short* __restrict__ out, int n4)
{
    for (int i = blockIdx.x*256 + threadIdx.x; i < n4; i += gridDim.x*256) {
        float4 v = ((const float4*)in)[i];
        ushort4 o;
        o.x = f2bf(v.x); o.y = f2bf(v.y); o.z = f2bf(v.z); o.w = f2bf(v.w);
        ((ushort4*)out)[i] = o;
    }
}

// ---------------- embedding gather ----------------
__global__ void embed_kernel(const int* __restrict__ idx, const float* __restrict__ emb,
                             float* __restrict__ x)
{
    int i = blockIdx.x*256 + threadIdx.x;        // over BL*DM
    if (i >= BL*DM) return;
    int c = i % DM; int bl = i / DM;
    x[i] = emb[(size_t)idx[bl]*DM + c];
}

// ---------------- rmsnorm single (bf16 out, final norm) ----------------
__global__ void rmsnorm_bf_kernel(const float* __restrict__ in, const float* __restrict__ w,
                                  unsigned short* __restrict__ out)
{
    int row = blockIdx.x;
    const float* xr = in + (size_t)row*DM;
    float ss = 0.f;
    for (int c = threadIdx.x; c < DM; c += 256) { float v = xr[c]; ss += v*v; }
    #pragma unroll
    for (int o = 32; o > 0; o >>= 1) ss += __shfl_down(ss, o, 64);
    __shared__ float red[4];
    if ((threadIdx.x & 63) == 0) red[threadIdx.x >> 6] = ss;
    __syncthreads();
    float tot = red[0] + red[1] + red[2] + red[3];
    float scale = rsqrtf(tot * (1.f/DM) + 1e-5f);
    for (int c = threadIdx.x; c < DM; c += 256)
        out[(size_t)row*DM + c] = f2bf(xr[c]*scale*w[c]);
}

// ---------------- prep_layer: rmsnorm(q,v) hi/lo + weight hi/lo casts --------
// blocks [0, 2*BL): rmsnorm rows; blocks [2*BL, 2*BL+1024): grid-stride casts
__global__ void prep_layer(
    const float* __restrict__ x, const float* __restrict__ vis, const float* __restrict__ w,
    unsigned short* __restrict__ qh, unsigned short* __restrict__ ql,
    unsigned short* __restrict__ vh, unsigned short* __restrict__ vl,
    const float* __restrict__ s1, unsigned short* __restrict__ h1, unsigned short* __restrict__ l1, int n1,
    const float* __restrict__ s2, unsigned short* __restrict__ h2, unsigned short* __restrict__ l2, int n2,
    const float* __restrict__ s3, unsigned short* __restrict__ h3, unsigned short* __restrict__ l3, int n3)
{
    if (blockIdx.x < 2*BL) {
        int row = blockIdx.x;
        bool first = row < BL;
        int r = first ? row : row - BL;
        const float* xr = (first ? x : vis) + (size_t)r*DM;
        unsigned short* oh = (first ? qh : vh) + (size_t)r*DM;
        unsigned short* ol = (first ? ql : vl) + (size_t)r*DM;
        float ss = 0.f;
        for (int c = threadIdx.x; c < DM; c += 256) { float v = xr[c]; ss += v*v; }
        #pragma unroll
        for (int o = 32; o > 0; o >>= 1) ss += __shfl_down(ss, o, 64);
        __shared__ float red[4];
        if ((threadIdx.x & 63) == 0) red[threadIdx.x >> 6] = ss;
        __syncthreads();
        float tot = red[0] + red[1] + red[2] + red[3];
        float scale = rsqrtf(tot * (1.f/DM) + 1e-5f);
        for (int c = threadIdx.x; c < DM; c += 256) {
            float v = xr[c]*scale*w[c];
            unsigned short h = f2bf(v);
            oh[c] = h;
            ol[c] = f2bf(v - bf2f(h));
        }
    } else {
        int total = n1 + n2 + n3;
        int nblk = gridDim.x - 2*BL;
        for (int i = (blockIdx.x - 2*BL)*256 + threadIdx.x; i < total; i += nblk*256) {
            const float* s; unsigned short *h, *l; int j;
            if (i < n1)           { s = s1; h = h1; l = l1; j = i; }
            else if (i < n1 + n2) { s = s2; h = h2; l = l2; j = i - n1; }
            else                  { s = s3; h = h3; l = l3; j = i - n1 - n2; }
            float4 v = ((const float4*)s)[j];
            ushort4 hh, ll;
            hh.x = f2bf(v.x); ll.x = f2bf(v.x - bf2f(hh.x));
            hh.y = f2bf(v.y); ll.y = f2bf(v.y - bf2f(hh.y));
            hh.z = f2bf(v.z); ll.z = f2bf(v.z - bf2f(hh.z));
            hh.w = f2bf(v.w); ll.w = f2bf(v.w - bf2f(hh.w));
            ((ushort4*)h)[j] = hh;
            ((ushort4*)l)[j] = ll;
        }
    }
}

// ---------------- lm_head bf16 MFMA GEMM (round-3 config: no swizzle) --------
// grid (x = N/128, y = M/128); plain cached stores.
__global__ __launch_bounds__(256) void gemm_head(
    const unsigned short* __restrict__ A, int lda,
    const unsigned short* __restrict__ W, int ldb,
    float* __restrict__ C, int ldc, int K)
{
    __shared__ unsigned short As[128*64];
    __shared__ unsigned short Bs[128*64];
    const int tid = threadIdx.x;
    const int bm = blockIdx.y*128, bn = blockIdx.x*128;
    const int l  = tid & 63;
    const int w  = tid >> 6;
    const int wr = (w >> 1)*64, wc = (w & 1)*64;
    const int lr = l & 15, lg = l >> 4;

    f32x4 zero4 = {0.f, 0.f, 0.f, 0.f};
    f32x4 acc[4][4];
    #pragma unroll
    for (int m = 0; m < 4; m++)
        #pragma unroll
        for (int n = 0; n < 4; n++) acc[m][n] = zero4;

    for (int k0 = 0; k0 < K; k0 += 64) {
        __syncthreads();
        #pragma unroll
        for (int i = 0; i < 4; i++) {
            int c   = i*256 + tid;
            int row = c >> 3;
            int kb  = c & 7;
            int kbs = (kb ^ (row & 7)) << 3;
            gload_lds16(A + (size_t)(bm+row)*lda + k0 + kbs, &As[c*8]);
            gload_lds16(W + (size_t)(bn+row)*ldb + k0 + kbs, &Bs[c*8]);
        }
        __syncthreads();
        #pragma unroll
        for (int kk = 0; kk < 2; kk++) {
            short8 af[4], bfr[4];
            #pragma unroll
            for (int m = 0; m < 4; m++) {
                int row = wr + m*16 + lr;
                af[m] = *(const short8*)&As[row*64 + (((kk*4+lg) ^ (row & 7)) << 3)];
            }
            #pragma unroll
            for (int n = 0; n < 4; n++) {
                int row = wc + n*16 + lr;
                bfr[n] = *(const short8*)&Bs[row*64 + (((kk*4+lg) ^ (row & 7)) << 3)];
            }
            #pragma unroll
            for (int m = 0; m < 4; m++)
                #pragma unroll
                for (int n = 0; n < 4; n++)
                    acc[m][n] = __builtin_amdgcn_mfma_f32_16x16x32_bf16(af[m], bfr[n], acc[m][n], 0, 0, 0);
        }
    }

    #pragma unroll
    for (int m = 0; m < 4; m++)
        #pragma unroll
        for (int n = 0; n < 4; n++) {
            int col = bn + wc + n*16 + lr;
            #pragma unroll
            for (int r = 0; r < 4; r++) {
                int rowi = bm + wr + m*16 + lg*4 + r;
                C[(size_t)rowi*ldc + col] = acc[m][n][r];
            }
        }
}

// ---------------- split-bf16 (hi/lo) MFMA GEMM core, BK=64 (round-4 cfg) -----
template<int EPI>
__device__ __forceinline__ void mfma2_body(
    const unsigned short* __restrict__ Ah, const unsigned short* __restrict__ Alo, int lda,
    const unsigned short* __restrict__ Wh, const unsigned short* __restrict__ Wlo, int ldb,
    float* __restrict__ C, int ldc, const float* __restrict__ extra,
    int K, int bm, int bn,
    unsigned short* Ash, unsigned short* Asl, unsigned short* Bsh, unsigned short* Bsl)
{
    const int tid = threadIdx.x;
    const int l  = tid & 63;
    const int w  = tid >> 6;
    const int wr = (w >> 1)*64, wc = (w & 1)*64;
    const int lr = l & 15, lg = l >> 4;

    f32x4 zero4 = {0.f, 0.f, 0.f, 0.f};
    f32x4 acc[4][4];
    #pragma unroll
    for (int m = 0; m < 4; m++)
        #pragma unroll
        for (int n = 0; n < 4; n++) acc[m][n] = zero4;

    for (int k0 = 0; k0 < K; k0 += 64) {
        __syncthreads();
        #pragma unroll
        for (int i = 0; i < 4; i++) {
            int c   = i*256 + tid;
            int row = c >> 3;
            int kb  = c & 7;
            int kbs = (kb ^ (row & 7)) << 3;
            const size_t ao = (size_t)(bm+row)*lda + k0 + kbs;
            const size_t bo = (size_t)(bn+row)*ldb + k0 + kbs;
            gload_lds16(Ah  + ao, &Ash[c*8]);
            gload_lds16(Alo + ao, &Asl[c*8]);
            gload_lds16(Wh  + bo, &Bsh[c*8]);
            gload_lds16(Wlo + bo, &Bsl[c*8]);
        }
        __syncthreads();
        #pragma unroll
        for (int kk = 0; kk < 2; kk++) {
            short8 ah[4], al[4], bh[4], bl[4];
            #pragma unroll
            for (int m = 0; m < 4; m++) {
                int row = wr + m*16 + lr;
                int so  = row*64 + (((kk*4 + lg) ^ (row & 7)) << 3);
                ah[m] = *(const short8*)&Ash[so];
                al[m] = *(const short8*)&Asl[so];
            }
            #pragma unroll
            for (int n = 0; n < 4; n++) {
                int row = wc + n*16 + lr;
                int so  = row*64 + (((kk*4 + lg) ^ (row & 7)) << 3);
                bh[n] = *(const short8*)&Bsh[so];
                bl[n] = *(const short8*)&Bsl[so];
            }
            #pragma unroll
            for (int m = 0; m < 4; m++)
                #pragma unroll
                for (int n = 0; n < 4; n++) {
                    acc[m][n] = __builtin_amdgcn_mfma_f32_16x16x32_bf16(al[m], bh[n], acc[m][n], 0, 0, 0);
                    acc[m][n] = __builtin_amdgcn_mfma_f32_16x16x32_bf16(ah[m], bl[n], acc[m][n], 0, 0, 0);
                    acc[m][n] = __builtin_amdgcn_mfma_f32_16x16x32_bf16(ah[m], bh[n], acc[m][n], 0, 0, 0);
                }
        }
    }

    #pragma unroll
    for (int m = 0; m < 4; m++)
        #pragma unroll
        for (int n = 0; n < 4; n++) {
            int col = bn + wc + n*16 + lr;
            #pragma unroll
            for (int r = 0; r < 4; r++) {
                int rowi = bm + wr + m*16 + lg*4 + r;
                float v = acc[m][n][r];
                if (EPI == 1) v += extra[(size_t)rowi*ldc + col];
                C[(size_t)rowi*ldc + col] = v;
            }
        }
}

// single split GEMM (out_proj, EPI=1 residual)
template<int EPI>
__global__ __launch_bounds__(256) void gemm_mfma2(
    const unsigned short* __restrict__ Ah, const unsigned short* __restrict__ Alo, int lda,
    const unsigned short* __restrict__ Wh, const unsigned short* __restrict__ Wlo, int ldb,
    float* __restrict__ C, int ldc, const float* __restrict__ extra, int K)
{
    __shared__ unsigned short Ash[128*64];
    __shared__ unsigned short Asl[128*64];
    __shared__ unsigned short Bsh[128*64];
    __shared__ unsigned short Bsl[128*64];
    mfma2_body<EPI>(Ah, Alo, lda, Wh, Wlo, ldb, C, ldc, extra, K,
                    blockIdx.y*128, blockIdx.x*128, Ash, Asl, Bsh, Bsl);
}

// dual split GEMM: blocks [0,nb1) -> GEMM1, [nb1,..) -> GEMM2 (shared lda/ldb/K)
__global__ __launch_bounds__(256) void gemm_mfma2_dual(
    const unsigned short* __restrict__ Ah1, const unsigned short* __restrict__ Al1,
    const unsigned short* __restrict__ Wh1, const unsigned short* __restrict__ Wl1,
    float* __restrict__ C1, int ldc1, int nb1,
    const unsigned short* __restrict__ Ah2, const unsigned short* __restrict__ Al2,
    const unsigned short* __restrict__ Wh2, const unsigned short* __restrict__ Wl2,
    float* __restrict__ C2, int ldc2,
    int lda, int ldb, int K)
{
    __shared__ unsigned short Ash[128*64];
    __shared__ unsigned short Asl[128*64];
    __shared__ unsigned short Bsh[128*64];
    __shared__ unsigned short Bsl[128*64];
    int bx = blockIdx.x;
    if (bx < nb1)
        mfma2_body<0>(Ah1, Al1, lda, Wh1, Wl1, ldb, C1, ldc1, nullptr, K,
                      blockIdx.y*128, bx*128, Ash, Asl, Bsh, Bsl);
    else
        mfma2_body<0>(Ah2, Al2, lda, Wh2, Wl2, ldb, C2, ldc2, nullptr, K,
                      blockIdx.y*128, (bx-nb1)*128, Ash, Asl, Bsh, Bsl);
}

// ---------------- fp32 tile GEMM (dt_proj, K=48, EPI=2 softplus+bias) ----------
template<int EPI>
__global__ __launch_bounds__(256) void gemm_tile(
    const float* __restrict__ A, int lda,
    const float* __restrict__ W, int ldb,
    float* __restrict__ C, int ldc,
    const float* __restrict__ extra,
    int K)
{
    __shared__ float As[8][128];
    __shared__ float Bs[8][128];
    const int bm = blockIdx.y * 128;
    const int bn = blockIdx.x * 128;
    const int tid = threadIdx.x;
    const int lr = tid >> 1;
    const int lh = (tid & 1) * 4;
    const int tr = tid >> 4;
    const int tc = tid & 15;

    float acc[8][8];
    #pragma unroll
    for (int i = 0; i < 8; i++)
        #pragma unroll
        for (int j = 0; j < 8; j++) acc[i][j] = 0.f;

    const float* Arow = A + (size_t)(bm + lr)*lda + lh;
    const float* Wrow = W + (size_t)(bn + lr)*ldb + lh;

    for (int k0 = 0; k0 < K; k0 += 8) {
        float4 av = *(const float4*)(Arow + k0);
        float4 wv = *(const float4*)(Wrow + k0);
        __syncthreads();
        As[lh+0][lr] = av.x; As[lh+1][lr] = av.y; As[lh+2][lr] = av.z; As[lh+3][lr] = av.w;
        Bs[lh+0][lr] = wv.x; Bs[lh+1][lr] = wv.y; Bs[lh+2][lr] = wv.z; Bs[lh+3][lr] = wv.w;
        __syncthreads();
        #pragma unroll
        for (int k = 0; k < 8; k++) {
            float a[8], b[8];
            *(float4*)(a)   = *(const float4*)&As[k][tr*8];
            *(float4*)(a+4) = *(const float4*)&As[k][tr*8+4];
            *(float4*)(b)   = *(const float4*)&Bs[k][tc*8];
            *(float4*)(b+4) = *(const float4*)&Bs[k][tc*8+4];
            #pragma unroll
            for (int i = 0; i < 8; i++)
                #pragma unroll
                for (int j = 0; j < 8; j++)
                    acc[i][j] = fmaf(a[i], b[j], acc[i][j]);
        }
    }

    #pragma unroll
    for (int i = 0; i < 8; i++) {
        int row = bm + tr*8 + i;
        float* crow = C + (size_t)row*ldc + bn + tc*8;
        float v[8];
        if (EPI == 2) {
            const float* bia = extra + bn + tc*8;
            #pragma unroll
            for (int j = 0; j < 8; j++) v[j] = softplusf_(acc[i][j] + bia[j]);
        } else {
            #pragma unroll
            for (int j = 0; j < 8; j++) v[j] = acc[i][j];
        }
        *(float4*)(crow)   = make_float4(v[0],v[1],v[2],v[3]);
        *(float4*)(crow+4) = make_float4(v[4],v[5],v[6],v[7]);
    }
}

// ---------------- fused skinny GEMM (no split-K): x_dbl(64) + C(16) -> xdbl ---
// grid: x = 5 (0..3 -> x_proj 16-col chunks on A1; 4 -> c_proj on A2), y = BL/64
__global__ __launch_bounds__(256) void gemm_skinny2(
    const float* __restrict__ A1, const float* __restrict__ A2, int lda,
    const float* __restrict__ W1, const float* __restrict__ W2, int ldb,
    float* __restrict__ outx, int K)
{
    __shared__ float As[64][36];
    __shared__ float Ws[16][36];
    int tid = threadIdx.x;
    int bx = blockIdx.x;
    bool isC = (bx == 4);
    const float* A = isC ? A2 : A1;
    const float* W = isC ? W2 : W1;
    int bn = isC ? 0 : bx*16;
    int colbase = isC ? 64 : bx*16;
    int bm = blockIdx.y*64;
    int ar = tid >> 2, ak = (tid & 3)*8;
    int wr = tid >> 4, wk = (tid & 15)*2;
    int tr = tid >> 4, tc = tid & 15;

    float acc[4] = {0.f,0.f,0.f,0.f};
    for (int k0 = 0; k0 < K; k0 += 32) {
        float4 a0 = *(const float4*)(A + (size_t)(bm+ar)*lda + k0 + ak);
        float4 a1 = *(const float4*)(A + (size_t)(bm+ar)*lda + k0 + ak + 4);
        float2 wv = *(const float2*)(W + (size_t)(bn+wr)*ldb + k0 + wk);
        __syncthreads();
        *(float4*)&As[ar][ak]   = a0;
        *(float4*)&As[ar][ak+4] = a1;
        Ws[wr][wk] = wv.x; Ws[wr][wk+1] = wv.y;
        __syncthreads();
        #pragma unroll
        for (int k = 0; k < 32; k += 4) {
            float4 wv4 = *(const float4*)&Ws[tc][k];
            #pragma unroll
            for (int i = 0; i < 4; i++) {
                float4 av4 = *(const float4*)&As[tr*4+i][k];
                acc[i] = fmaf(av4.x, wv4.x, acc[i]);
                acc[i] = fmaf(av4.y, wv4.y, acc[i]);
                acc[i] = fmaf(av4.z, wv4.z, acc[i]);
                acc[i] = fmaf(av4.w, wv4.w, acc[i]);
            }
        }
    }
    #pragma unroll
    for (int i = 0; i < 4; i++)
        outx[(size_t)(bm + tr*4 + i)*NXD + colbase + tc] = acc[i];
}

// ---------------- depthwise causal conv (k=4) + bias + silu ----------------
__global__ void conv_silu_kernel(const float* __restrict__ xr, const float* __restrict__ cw,
                                 const float* __restrict__ cb, float* __restrict__ t)
{
    int i = blockIdx.x*256 + threadIdx.x;     // over BL*DI
    if (i >= BL*DI) return;
    int d = i % DI; int bl = i / DI; int l = bl % L_; int b = bl / L_;
    const float* base = xr + (size_t)b*L_*(2*DI);
    float acc = cb[d];
    #pragma unroll
    for (int q = 0; q < 4; q++) {
        int ll = l - 3 + q;
        if (ll >= 0) acc = fmaf(base[(size_t)ll*(2*DI) + d], cw[d*4+q], acc);
    }
    t[i] = siluf_(acc);
}

// ---------------- fused selective scan (p1+p2+p3 in one kernel) ----------------
// grid: B_ * DI/DTILE blocks; 256 threads = (dl 0..7) x (chunk c 0..31).
// Phase1: per-chunk (P,S) -> LDS. Phase2: 128-thread cross-chunk prefix in LDS
// (S slot overwritten with h_init). Phase3: replay chunk, fuse y + u*D and
// z = y*silu(res) -> bf16 hi/lo.
__global__ __launch_bounds__(256) void scan_fused(
    const float* __restrict__ delta, const float* __restrict__ t,
    const float* __restrict__ xdbl,
    const float* __restrict__ A_log, const float* __restrict__ Dp,
    const float* __restrict__ xr,
    unsigned short* __restrict__ zh, unsigned short* __restrict__ zl)
{
    __shared__ float P_lds[256*17];
    __shared__ float S_lds[256*17];
    int blk = blockIdx.x;
    int b  = blk / (DI/DTILE);
    int d0 = (blk % (DI/DTILE))*DTILE;
    int tid = threadIdx.x;
    int dl = tid & 7, c = tid >> 3;
    int d = d0 + dl;

    float Ad[16];
    #pragma unroll
    for (int n = 0; n < 16; n++) Ad[n] = -expf(A_log[d*16+n]);

    // ---- phase 1: chunk summary ----
    float P[16], S[16];
    #pragma unroll
    for (int n = 0; n < 16; n++) { P[n] = 1.f; S[n] = 0.f; }
    for (int s = 0; s < LCH; s++) {
        int bl = b*L_ + c*LCH + s;
        float dt = delta[(size_t)bl*DI + d];
        float u  = t[(size_t)bl*DI + d];
        const float4* Bp4 = (const float4*)(xdbl + (size_t)bl*NXD + 48);
        float Bv[16];
        #pragma unroll
        for (int q = 0; q < 4; q++) {
            float4 bv = Bp4[q];
            Bv[q*4+0]=bv.x; Bv[q*4+1]=bv.y; Bv[q*4+2]=bv.z; Bv[q*4+3]=bv.w;
        }
        float du = dt*u;
        #pragma unroll
        for (int n = 0; n < 16; n++) {
            float a = expf(dt*Ad[n]);
            P[n] *= a;
            S[n] = fmaf(a, S[n], du*Bv[n]);
        }
    }
    #pragma unroll
    for (int n = 0; n < 16; n++) { P_lds[tid*17+n] = P[n]; S_lds[tid*17+n] = S[n]; }
    __syncthreads();

    // ---- phase 2: cross-chunk prefix (128 threads: (dl2, n2)) ----
    if (tid < 128) {
        int dl2 = tid >> 4, n2 = tid & 15;
        float h = 0.f;
        for (int cc = 0; cc < NCH; cc++) {
            int slot = cc*8 + dl2;
            float p = P_lds[slot*17 + n2];
            float s = S_lds[slot*17 + n2];
            S_lds[slot*17 + n2] = h;          // h_init for chunk cc
            h = fmaf(p, h, s);
        }
    }
    __syncthreads();

    // ---- phase 3: replay with h_init, fused epilogue ----
    float h[16];
    #pragma unroll
    for (int n = 0; n < 16; n++) h[n] = S_lds[tid*17+n];
    float Dd = Dp[d];
    for (int s = 0; s < LCH; s++) {
        int bl = b*L_ + c*LCH + s;
        float dt = delta[(size_t)bl*DI + d];
        float u  = t[(size_t)bl*DI + d];
        const float4* Bp4 = (const float4*)(xdbl + (size_t)bl*NXD + 48);
        const float4* Cp4 = (const float4*)(xdbl + (size_t)bl*NXD + 64);
        float Bv[16], Cv[16];
        #pragma unroll
        for (int q = 0; q < 4; q++) {
            float4 bv = Bp4[q]; float4 cv = Cp4[q];
            Bv[q*4+0]=bv.x; Bv[q*4+1]=bv.y; Bv[q*4+2]=bv.z; Bv[q*4+3]=bv.w;
            Cv[q*4+0]=cv.x; Cv[q*4+1]=cv.y; Cv[q*4+2]=cv.z; Cv[q*4+3]=cv.w;
        }
        float du = dt*u;
        float y = 0.f;
        #pragma unroll
        for (int n = 0; n < 16; n++) {
            float a = expf(dt*Ad[n]);
            h[n] = fmaf(a, h[n], du*Bv[n]);
            y = fmaf(h[n], Cv[n], y);
        }
        y = fmaf(u, Dd, y);
        float r = xr[(size_t)bl*(2*DI) + DI + d];
        float zv = y * siluf_(r);
        unsigned short hh = f2bf(zv);
        zh[(size_t)bl*DI + d] = hh;
        zl[(size_t)bl*DI + d] = f2bf(zv - bf2f(hh));
    }
}

// ---------------- host ----------------
extern "C" void kernel_launch(void* const* d_in, const int* in_sizes, int n_in,
                              void* d_out, int out_size, void* d_ws, size_t ws_size,
                              hipStream_t stream)
{
    const int*   text     = (const int*)  d_in[0];
    const float* visual   = (const float*)d_in[1];
    const float* emb      = (const float*)d_in[2];
    const float* norm_w   = (const float*)d_in[3];
    const float* norm_f_w = (const float*)d_in[4];
    const float* in_proj  = (const float*)d_in[5];
    const float* in_proj2 = (const float*)d_in[6];
    const float* conv_w   = (const float*)d_in[7];
    const float* conv_b   = (const float*)d_in[8];
    const float* x_proj   = (const float*)d_in[9];
    const float* c_proj   = (const float*)d_in[10];
    const float* dt_w     = (const float*)d_in[11];
    const float* dt_b     = (const float*)d_in[12];
    const float* A_log    = (const float*)d_in[13];
    const float* Dp       = (const float*)d_in[14];
    const float* out_proj = (const float*)d_in[15];
    float* out = (float*)d_out;

    // workspace layout (floats first)
    float* ws = (float*)d_ws;
    size_t off = 0;
    float* x     = ws + off; off += (size_t)BL*DM;
    float* xr    = ws + off; off += (size_t)BL*2*DI;
    float* vin   = ws + off; off += (size_t)BL*DI;
    float* tb    = ws + off; off += (size_t)BL*DI;
    float* dl    = ws + off; off += (size_t)BL*DI;
    float* xdbl  = ws + off; off += (size_t)BL*NXD;

    unsigned short* bfb = (unsigned short*)(ws + off);
    size_t bo = 0;
    unsigned short* emb_bf = bfb + bo; bo += (size_t)VOC*DM;
    unsigned short* wA_h   = bfb + bo; bo += (size_t)2*DI*DM;
    unsigned short* wA_l   = bfb + bo; bo += (size_t)2*DI*DM;
    unsigned short* wB_h   = bfb + bo; bo += (size_t)DI*DM;
    unsigned short* wB_l   = bfb + bo; bo += (size_t)DI*DM;
    unsigned short* wO_h   = bfb + bo; bo += (size_t)DM*DI;
    unsigned short* wO_l   = bfb + bo; bo += (size_t)DM*DI;
    unsigned short* q_h    = bfb + bo; bo += (size_t)BL*DM;
    unsigned short* q_l    = bfb + bo; bo += (size_t)BL*DM;
    unsigned short* v_h    = bfb + bo; bo += (size_t)BL*DM;
    unsigned short* v_l    = bfb + bo; bo += (size_t)BL*DM;
    unsigned short* z_h    = bfb + bo; bo += (size_t)BL*DI;
    unsigned short* z_l    = bfb + bo; bo += (size_t)BL*DI;
    unsigned short* xn_bf  = bfb + bo; bo += (size_t)BL*DM;

    dim3 blk(256);

    // embedding cast once (lm_head B operand)
    cast_bf16_kernel<<<dim3(2048), blk, 0, stream>>>(emb, emb_bf, VOC*DM/4);

    embed_kernel<<<dim3((BL*DM)/256), blk, 0, stream>>>(text, emb, x);

    for (int i = 0; i < NL; i++) {
        const float* nw = norm_w + (size_t)i*DM;

        // rmsnorm(q,v) hi/lo + weight hi/lo casts, one dispatch
        prep_layer<<<dim3(2*BL + 1024), blk, 0, stream>>>(
            x, visual, nw, q_h, q_l, v_h, v_l,
            in_proj  + (size_t)i*2*DI*DM, wA_h, wA_l, 2*DI*DM/4,
            in_proj2 + (size_t)i*DI*DM,   wB_h, wB_l, DI*DM/4,
            out_proj + (size_t)i*DM*DI,   wO_h, wO_l, DM*DI/4);

        // xr = q @ in_proj^T (N=3072) ++ vin = v @ in_proj2^T (N=1536), fused
        gemm_mfma2_dual<<<dim3(2*DI/128 + DI/128, BL/128), blk, 0, stream>>>(
            q_h, q_l, wA_h, wA_l, xr, 2*DI, 2*DI/128,
            v_h, v_l, wB_h, wB_l, vin, DI,
            DM, DM, DM);

        conv_silu_kernel<<<dim3((BL*DI)/256), blk, 0, stream>>>(
            xr, conv_w + (size_t)i*DI*4, conv_b + (size_t)i*DI, tb);

        // x_dbl (t @ x_proj^T) ++ C (vin @ c_proj^T) -> xdbl[BL][80] direct
        gemm_skinny2<<<dim3(5, BL/64), blk, 0, stream>>>(
            tb, vin, DI, x_proj + (size_t)i*(DR+DS)*DI, c_proj + (size_t)i*DS*DI, DI,
            xdbl, DI);

        // delta = softplus(x_dbl[:, :48] @ dt_w^T + dt_b) fp32
        gemm_tile<2><<<dim3(DI/128, BL/128), blk, 0, stream>>>(
            xdbl, NXD, dt_w + (size_t)i*DI*DR, DR, dl, DI, dt_b + (size_t)i*DI, DR);

        // fused selective scan -> z hi/lo
        scan_fused<<<dim3(B_*DI/DTILE), blk, 0, stream>>>(
            dl, tb, xdbl, A_log + (size_t)i*DI*DS, Dp + (size_t)i*DI, xr, z_h, z_l);

        // x = z @ out_proj^T + x (split precision)
        gemm_mfma2<1><<<dim3(DM/128, BL/128), blk, 0, stream>>>(
            z_h, z_l, DI, wO_h, wO_l, DI, x, DM, x, DI);
    }

    rmsnorm_bf_kernel<<<dim3(BL), blk, 0, stream>>>(x, norm_f_w, xn_bf);
    // logits = xn @ emb^T (2048 x 32000, K=768)
    gemm_head<<<dim3(VOC/128, BL/128), blk, 0, stream>>>(
        xn_bf, DM, emb_bf, DM, out, VOC, DM);
}